// Round 2
// baseline (403.680 us; speedup 1.0000x reference)
//
#include <hip/hip_runtime.h>

#define NFEAT 256
#define GS 32
#define NG 8
#define BATCH 32
#define HW 4096
#define NTOT (BATCH*HW)   // 131072 samples per channel
#define EPSV 1e-5f

// ws layout (float offsets)
#define RPART_SZ (NG*64*1024)                 // 524288 floats
#define SPART_OFF (RPART_SZ)                  // 8*64*32 = 16384
#define WMT_OFF   (SPART_OFF + NG*64*32)      // 8*1024
#define BETA_OFF  (WMT_OFF + NG*1024)         // 8*32

// ---------------------------------------------------------------------------
// Kernel 1: per-(g,b,half) partial raw gram R = X X^T and channel sums S.
// R2 fixed the VGPR spill (WRITE 328MB -> 2MB) but left 2 waves/SIMD ->
// latency-bound at VALUBusy 20%, Occupancy 22%, dur 169us.
// R3: same 512 blocks, 1024 threads (16 waves x 128 samples). VGPR ~48 ->
// 8 waves/SIMD (32 waves/CU), 4x TLP to hide the L1-hit load latency.
// Inner loop unchanged (verified correct). Epilogue LDS padded to 17 floats
// per tile to kill the 32-way bank conflict (was 393K conflict cycles).
// ---------------------------------------------------------------------------
__global__ __launch_bounds__(1024, 4) void dbn_stats(const float* __restrict__ x,
                                                     float* __restrict__ Rpart,
                                                     float* __restrict__ Spart) {
    int bx = blockIdx.x;            // 0..511
    int g  = bx >> 6;
    int pb = bx & 63;               // b*2 + h
    int b  = pb >> 1, h = pb & 1;
    int tid = threadIdx.x;
    int w  = tid >> 6;              // wave 0..15 (sample-split: 128 each)
    int t  = tid & 63;
    int tr = t >> 3, tc = t & 7;    // 8x8 tile grid; tile = 4 rows x 4 cols

    const float* xg = x + ((size_t)(b*NFEAT + g*GS))*HW + h*2048 + w*128;
    const float* rp0 = xg + (size_t)(tr*4)*HW;
    const float* cp0 = xg + (size_t)(tc*4)*HW;

    float acc[4][4];
    float srow[4];
    #pragma unroll
    for (int i = 0; i < 4; ++i) {
        srow[i] = 0.f;
        #pragma unroll
        for (int j = 0; j < 4; ++j) acc[i][j] = 0.f;
    }

    #pragma unroll 2
    for (int it = 0; it < 32; ++it) {   // 128 samples / 4 per float4
        int s = it*4;
        float4 ra[4], cb[4];
        #pragma unroll
        for (int i = 0; i < 4; ++i) ra[i] = *(const float4*)(rp0 + (size_t)i*HW + s);
        #pragma unroll
        for (int j = 0; j < 4; ++j) cb[j] = *(const float4*)(cp0 + (size_t)j*HW + s);

        #pragma unroll
        for (int i = 0; i < 4; ++i) {
            #pragma unroll
            for (int j = 0; j < 4; ++j) {
                float a = acc[i][j];
                a = fmaf(ra[i].x, cb[j].x, a);
                a = fmaf(ra[i].y, cb[j].y, a);
                a = fmaf(ra[i].z, cb[j].z, a);
                a = fmaf(ra[i].w, cb[j].w, a);
                acc[i][j] = a;
            }
            srow[i] += (ra[i].x + ra[i].y) + (ra[i].z + ra[i].w);
        }
    }

    // cross-wave reduction via LDS (epilogue, once per block).
    // [..][17] padding: lane-base t*17 is odd-stride -> conflict-free writes.
    __shared__ float red[16][64][17];   // ~69.6 KB
    __shared__ float sred[16][8][4];    // 2 KB
    #pragma unroll
    for (int i = 0; i < 4; ++i)
        #pragma unroll
        for (int j = 0; j < 4; ++j)
            red[w][t][i*4 + j] = acc[i][j];
    if (tc == 0) {
        #pragma unroll
        for (int i = 0; i < 4; ++i) sred[w][tr][i] = srow[i];
    }
    __syncthreads();

    // 1024 threads <-> 1024 gram entries: 16 LDS reads + 1 coalesced store.
    float* Rp = Rpart + (size_t)(g*64 + pb)*1024;
    {
        int c = tid >> 5, d = tid & 31;
        int tile = (c >> 2)*8 + (d >> 2);
        int slot = (c & 3)*4 + (d & 3);
        float s = 0.f;
        #pragma unroll
        for (int ww = 0; ww < 16; ++ww) s += red[ww][tile][slot];
        Rp[tid] = s;
    }
    if (tid < 32) {
        int c = tid;
        float s = 0.f;
        #pragma unroll
        for (int ww = 0; ww < 16; ++ww) s += sred[ww][c>>2][c&3];
        Spart[(size_t)(g*64 + pb)*32 + c] = s;
    }
}

// ---------------------------------------------------------------------------
// Kernel 2: per-group solver. 1024 threads, 1 gram entry per thread.
// Reduce partials, sigma = R - S S^T/N + eps I, Newton-Schulz inverse sqrt
// (8 iters), fold weight/bias/mean into wmT/beta.
// ---------------------------------------------------------------------------
__global__ __launch_bounds__(1024) void dbn_solver(const float* __restrict__ Rpart, const float* __restrict__ Spart,
                           const float* __restrict__ weight, const float* __restrict__ bias,
                           float* __restrict__ wmT, float* __restrict__ beta) {
    __shared__ float Y[1024], Z[1024], T[1024], S[32], M[32];
    __shared__ float sh_s;
    int g = blockIdx.x;
    int tid = threadIdx.x;
    int c = tid >> 5, d = tid & 31;

    if (tid < 32) {
        float s = 0.f;
        #pragma unroll 4
        for (int pb = 0; pb < 64; ++pb) s += Spart[(size_t)(g*64 + pb)*32 + tid];
        S[tid] = s;
        M[tid] = s / (float)NTOT;
    }
    float rs = 0.f;
    #pragma unroll 4
    for (int pb = 0; pb < 64; ++pb) rs += Rpart[(size_t)(g*64 + pb)*1024 + tid];
    __syncthreads();

    const float invN = 1.0f/(float)NTOT;
    float v = rs - S[c]*S[d]*invN;
    if (c == d) v += EPSV;
    T[tid] = v;
    __syncthreads();

    if (tid == 0) {
        float tr = 0.f;
        for (int k = 0; k < 32; ++k) tr += T[k*33];
        sh_s = tr / 32.0f;
    }
    __syncthreads();
    float sc = sh_s;
    float invs = 1.0f / sc;

    Y[tid] = v * invs;
    Z[tid] = (c == d) ? 1.0f : 0.0f;
    __syncthreads();

    for (int it = 0; it < 8; ++it) {
        float s2 = 0.f;
        #pragma unroll
        for (int k = 0; k < 32; ++k) s2 = fmaf(Z[c*32 + k], Y[k*32 + d], s2);
        float a = ((c == d) ? 3.0f : 0.0f) - s2;
        __syncthreads();
        T[tid] = a;
        __syncthreads();
        float sy = 0.f, sz = 0.f;
        #pragma unroll
        for (int k = 0; k < 32; ++k) {
            sy = fmaf(Y[c*32 + k], T[k*32 + d], sy);
            sz = fmaf(T[c*32 + k], Z[k*32 + d], sz);
        }
        __syncthreads();
        Y[tid] = 0.5f*sy;
        Z[tid] = 0.5f*sz;
        __syncthreads();
    }

    float wfac = rsqrtf(sc);   // sigma^{-1/2} = Z / sqrt(s)
    wmT[(size_t)g*1024 + d*32 + c] = Z[tid]*wfac*weight[g*GS + c];  // transposed + weight-folded
    if (tid < 32) {
        float s2 = 0.f;
        #pragma unroll
        for (int k = 0; k < 32; ++k) s2 = fmaf(Z[tid*32 + k], M[k], s2);
        beta[g*GS + tid] = -s2*wfac*weight[g*GS + tid] + bias[g*GS + tid];
    }
}

// ---------------------------------------------------------------------------
// Kernel 3: whiten. out[c] = sum_d wmT[d][c] * x[d] + beta[c].
// One thread per spatial position; wm/beta indices are wave-uniform -> s_load,
// inner loop is pure v_fmac(v, s, v). Memory-bound: 134 MB in + 134 MB out.
// R3: non-temporal stores (output never re-read; avoid L2 write-allocate
// pollution). Structure otherwise unchanged pending counters.
// ---------------------------------------------------------------------------
__global__ __launch_bounds__(256, 4) void dbn_whiten(const float* __restrict__ x,
                                                     const float* __restrict__ wmT,
                                                     const float* __restrict__ beta,
                                                     float* __restrict__ out) {
    int bx = blockIdx.x;            // 0..4095
    int gb = bx >> 4;               // 0..255
    int chunk = bx & 15;
    int b = gb >> 3, g = gb & 7;
    size_t base = ((size_t)(b*NFEAT + g*GS))*HW + chunk*256 + threadIdx.x;
    const float* wg = wmT + (size_t)g*1024;
    const float* bg = beta + (size_t)g*GS;

    float v[32];
    #pragma unroll
    for (int d = 0; d < 32; ++d) v[d] = x[base + (size_t)d*HW];

    float acc[32];
    #pragma unroll
    for (int c = 0; c < 32; ++c) acc[c] = bg[c];

    #pragma unroll
    for (int d = 0; d < 32; ++d) {
        float vd = v[d];
        #pragma unroll
        for (int c = 0; c < 32; ++c) acc[c] = fmaf(wg[d*32 + c], vd, acc[c]);
    }

    #pragma unroll
    for (int c = 0; c < 32; ++c)
        __builtin_nontemporal_store(acc[c], &out[base + (size_t)c*HW]);
}

extern "C" void kernel_launch(void* const* d_in, const int* in_sizes, int n_in,
                              void* d_out, int out_size, void* d_ws, size_t ws_size,
                              hipStream_t stream) {
    const float* x      = (const float*)d_in[0];
    const float* weight = (const float*)d_in[1];
    const float* bias   = (const float*)d_in[2];
    float* out = (float*)d_out;
    float* ws  = (float*)d_ws;

    float* Rpart = ws;
    float* Spart = ws + SPART_OFF;
    float* wmT   = ws + WMT_OFF;
    float* beta  = ws + BETA_OFF;

    dbn_stats <<<512, 1024, 0, stream>>>(x, Rpart, Spart);
    dbn_solver<<<NG, 1024, 0, stream>>>(Rpart, Spart, weight, bias, wmT, beta);
    dbn_whiten<<<4096, 256, 0, stream>>>(x, wmT, beta, out);
}